// Round 11
// baseline (126.162 us; speedup 1.0000x reference)
//
#include <hip/hip_runtime.h>

// B=4, N=4096, D=128 fixed by the reference setup.
// d_ws layout: [0, 4MiB) h as bf16 bits (ushort), [4MiB, +64KiB) sq fp32.

typedef float  f32x4   __attribute__((ext_vector_type(4)));
typedef float  f32x16  __attribute__((ext_vector_type(16)));
typedef short  bf16x8  __attribute__((ext_vector_type(8)));
typedef __attribute__((address_space(3))) void       lds_void_t;
typedef const __attribute__((address_space(1))) void gvoid_t;

__device__ inline float bf2f(unsigned int u) {
    union { unsigned int i; float f; } c; c.i = u << 16; return c.f;
}
__device__ inline unsigned short f2bf(float f) {
    union { float f; unsigned int i; } c; c.f = f;
    unsigned int r = c.i + 0x7fffu + ((c.i >> 16) & 1u);   // RNE
    return (unsigned short)(r >> 16);
}

// ---------------- Kernel A: h = bf16(x @ W^T + b), plus sq[row] = ||h_row||^2 ----
#define KA_ROWS 32
__global__ __launch_bounds__(256) void proj_kernel(
    const float* __restrict__ x, const float* __restrict__ W,
    const float* __restrict__ bias, unsigned short* __restrict__ h,
    float* __restrict__ sq)
{
    __shared__ __align__(16) unsigned short W5[32 * 4 * 32 * 4]; // 32 KiB
    __shared__ float xs[KA_ROWS][132];
    const int t = threadIdx.x;
    const long r0 = (long)blockIdx.x * KA_ROWS;

    for (int q = t; q < 4096; q += 256) {
        float4 w4 = ((const float4*)W)[q];
        int e = q >> 5, d4 = q & 31;
        int eb = e >> 2, ei = e & 3;
        ushort4 o;
        o.x = f2bf(w4.x); o.y = f2bf(w4.y); o.z = f2bf(w4.z); o.w = f2bf(w4.w);
        *(ushort4*)&W5[d4 * 256 + ei * 64 + ((eb ^ d4) & 31) * 4] = o;
    }
    const float4* xsrc = (const float4*)(x + r0 * 128);
    for (int q = t; q < KA_ROWS * 32; q += 256) {
        float4 v = xsrc[q];
        int r = q >> 5, d = (q & 31) << 2;
        xs[r][d] = v.x; xs[r][d + 1] = v.y; xs[r][d + 2] = v.z; xs[r][d + 3] = v.w;
    }
    __syncthreads();

    const int eb = t & 31, rb = t >> 5;
    const int e0 = eb * 4, rr0 = rb * 4;

    float acc_[4][4];
    #pragma unroll
    for (int ei = 0; ei < 4; ++ei) {
        float bv = bias[e0 + ei];
        #pragma unroll
        for (int ri = 0; ri < 4; ++ri) acc_[ri][ei] = bv;
    }

    for (int d4 = 0; d4 < 32; ++d4) {
        float wv[4][4];
        #pragma unroll
        for (int ei = 0; ei < 4; ++ei) {
            ushort4 u = *(const ushort4*)&W5[d4 * 256 + ei * 64 + ((eb ^ d4) & 31) * 4];
            wv[ei][0] = bf2f(u.x); wv[ei][1] = bf2f(u.y);
            wv[ei][2] = bf2f(u.z); wv[ei][3] = bf2f(u.w);
        }
        #pragma unroll
        for (int ri = 0; ri < 4; ++ri) {
            float4 xv = *(const float4*)&xs[rr0 + ri][d4 * 4];
            #pragma unroll
            for (int ei = 0; ei < 4; ++ei) {
                acc_[ri][ei] = fmaf(xv.x, wv[ei][0],
                               fmaf(xv.y, wv[ei][1],
                               fmaf(xv.z, wv[ei][2],
                               fmaf(xv.w, wv[ei][3], acc_[ri][ei]))));
            }
        }
    }

    float s[4] = {0.f, 0.f, 0.f, 0.f};
    #pragma unroll
    for (int ri = 0; ri < 4; ++ri) {
        ushort4 o;
        float v0 = bf2f(o.x = f2bf(acc_[ri][0]));
        float v1 = bf2f(o.y = f2bf(acc_[ri][1]));
        float v2 = bf2f(o.z = f2bf(acc_[ri][2]));
        float v3 = bf2f(o.w = f2bf(acc_[ri][3]));
        s[ri] = v0 * v0 + v1 * v1 + v2 * v2 + v3 * v3;
        *(ushort4*)&h[(r0 + rr0 + ri) * 128 + e0] = o;
    }
    #pragma unroll
    for (int ri = 0; ri < 4; ++ri) {
        #pragma unroll
        for (int m = 16; m > 0; m >>= 1) s[ri] += __shfl_xor(s[ri], m, 64);
    }
    if (eb == 0) {
        #pragma unroll
        for (int ri = 0; ri < 4; ++ri) sq[r0 + rr0 + ri] = s[ri];
    }
}

// ---------------- Kernel B: 256x256 tile, i-in-registers, 2 blocks/CU ----------
// Traffic same as R10 (2 B/elem: 64 KB i-frags + 64 KB j-panel per 256x256
// tile) but LDS cut to 65 KiB -> 2 blocks/CU resident. One barrier per block;
// afterwards waves run free with acc-reuse (16 VGPR) and stores distributed
// across the whole block. Co-resident block overlaps stage/drain phases.
__global__ __launch_bounds__(512, 4) void gram_kernel(
    const unsigned short* __restrict__ h, const float* __restrict__ sq,
    float* __restrict__ out)
{
    __shared__ __align__(16) unsigned short hsJ[256 * 128]; // 64 KiB
    __shared__ float sqj_s[256];                            // 1 KiB
    const int bid = blockIdx.x;                       // 1024 blocks
    const int xcd = bid & 7;
    const int bb  = xcd >> 1;                         // batch -> XCD pair
    const int tloc = ((bid >> 3) << 1) | (xcd & 1);   // 0..255 tile in batch
    const int it = tloc >> 4, jt = tloc & 15;
    const int i0 = bb * 4096 + it * 256;
    const int j0 = bb * 4096 + jt * 256;
    const int t = threadIdx.x, w = t >> 6, lane = t & 63;
    const int l31 = lane & 31, lh = lane >> 5;
    const char* hb = (const char*)h;

    // stage j-panel: linear LDS dest, inverse-swizzled source (rule #21)
    #pragma unroll
    for (int q = 0; q < 8; ++q) {
        int p   = (q * 512 + t) << 4;                 // linear byte off in panel
        int row = p >> 8;                             // 256 B per row
        int c   = (p >> 4) & 15;
        int cs  = c ^ (row & 15);
        __builtin_amdgcn_global_load_lds(
            (gvoid_t*)(hb + ((long)(j0 + row) << 8) + (cs << 4)),
            (lds_void_t*)(((char*)hsJ) + (unsigned)p), 16, 0, 0);
    }
    if (t < 256) sqj_s[t] = sq[j0 + t];

    // A-frags: wave w owns i-rows [w*32, w*32+32) (row = lane&31)
    bf16x8 af[8];
    {
        const char* base = hb + ((long)(i0 + w * 32 + l31) << 8);
        #pragma unroll
        for (int ks = 0; ks < 8; ++ks)
            af[ks] = *(const bf16x8*)(base + ((ks * 2 + lh) << 4));
    }
    // sq_i per acc reg (C/D row = (reg&3)+8*(reg>>2)+4*lh)
    float sqi_r[16];
    #pragma unroll
    for (int reg = 0; reg < 16; ++reg)
        sqi_r[reg] = sq[i0 + w * 32 + (reg & 3) + 8 * (reg >> 2) + 4 * lh];

    // per-reg store offsets (dwords from ob)
    float* ob = out + ((size_t)bb << 24) + ((size_t)(it * 256) << 12) + jt * 256;
    unsigned voff[16];
    #pragma unroll
    for (int reg = 0; reg < 16; ++reg) {
        int il = w * 32 + (reg & 3) + 8 * (reg >> 2) + 4 * lh;
        voff[reg] = ((unsigned)il << 12) + l31;
    }

    __syncthreads();
    const char* hJ = (const char*)hsJ;
    const bool diag = (it == jt);

    #pragma unroll
    for (int js = 0; js < 8; ++js) {
        const int rowB = js * 32 + l31;
        bf16x8 bg[8];
        #pragma unroll
        for (int ks = 0; ks < 8; ++ks) {
            int cB = ((ks * 2 + lh) ^ (rowB & 15)) << 4;
            bg[ks] = *(const bf16x8*)(hJ + (rowB << 8) + cB);
        }
        f32x16 acc = {};
        #pragma unroll
        for (int ks = 0; ks < 8; ++ks)
            acc = __builtin_amdgcn_mfma_f32_32x32x16_bf16(af[ks], bg[ks], acc, 0, 0, 0);

        const float sqj = sqj_s[rowB];
        #pragma unroll
        for (int reg = 0; reg < 16; ++reg) {
            float d2 = fmaxf(fmaf(acc[reg], -2.0f, sqi_r[reg] + sqj), 0.0f);
            float val = __expf(-sqrtf(d2));
            if (diag && w == js) {
                int rl = (reg & 3) + 8 * (reg >> 2) + 4 * lh;
                if (rl == l31) val = 1.0f;            // exact diagonal
            }
            __builtin_nontemporal_store(val, ob + voff[reg] + js * 32);
        }
    }
}

extern "C" void kernel_launch(void* const* d_in, const int* in_sizes, int n_in,
                              void* d_out, int out_size, void* d_ws, size_t ws_size,
                              hipStream_t stream) {
    const float* x = (const float*)d_in[0];   // [4,4096,128]
    const float* W = (const float*)d_in[1];   // [128,128]
    const float* b = (const float*)d_in[2];   // [128]
    float* out = (float*)d_out;               // [4,4096,4096]

    unsigned short* h = (unsigned short*)d_ws;                       // 16384*128 bf16
    float* sq = (float*)((char*)d_ws + (size_t)16384 * 128 * 2);     // 16384 fp32

    proj_kernel<<<dim3(16384 / KA_ROWS), dim3(256), 0, stream>>>(x, W, b, h, sq);
    gram_kernel<<<dim3(1024), dim3(512), 0, stream>>>(h, sq, out);
}

// Round 12
// 99.077 us; speedup vs baseline: 1.2734x; 1.2734x over previous
//
#include <hip/hip_runtime.h>

// B=4, N=4096, D=128 fixed by the reference setup.
// d_ws layout: [0, 4MiB) h as bf16 bits (ushort), [4MiB, +64KiB) sq fp32.

typedef float  f32x4   __attribute__((ext_vector_type(4)));
typedef float  f32x16  __attribute__((ext_vector_type(16)));
typedef short  bf16x8  __attribute__((ext_vector_type(8)));
typedef __attribute__((address_space(3))) void       lds_void_t;
typedef const __attribute__((address_space(1))) void gvoid_t;

__device__ inline float bf2f(unsigned int u) {
    union { unsigned int i; float f; } c; c.i = u << 16; return c.f;
}
__device__ inline unsigned short f2bf(float f) {
    union { float f; unsigned int i; } c; c.f = f;
    unsigned int r = c.i + 0x7fffu + ((c.i >> 16) & 1u);   // RNE
    return (unsigned short)(r >> 16);
}

// ---------------- Kernel A: h = bf16(x @ W^T + b), plus sq[row] = ||h_row||^2 ----
#define KA_ROWS 32
__global__ __launch_bounds__(256) void proj_kernel(
    const float* __restrict__ x, const float* __restrict__ W,
    const float* __restrict__ bias, unsigned short* __restrict__ h,
    float* __restrict__ sq)
{
    __shared__ __align__(16) unsigned short W5[32 * 4 * 32 * 4]; // 32 KiB
    __shared__ float xs[KA_ROWS][132];
    const int t = threadIdx.x;
    const long r0 = (long)blockIdx.x * KA_ROWS;

    for (int q = t; q < 4096; q += 256) {
        float4 w4 = ((const float4*)W)[q];
        int e = q >> 5, d4 = q & 31;
        int eb = e >> 2, ei = e & 3;
        ushort4 o;
        o.x = f2bf(w4.x); o.y = f2bf(w4.y); o.z = f2bf(w4.z); o.w = f2bf(w4.w);
        *(ushort4*)&W5[d4 * 256 + ei * 64 + ((eb ^ d4) & 31) * 4] = o;
    }
    const float4* xsrc = (const float4*)(x + r0 * 128);
    for (int q = t; q < KA_ROWS * 32; q += 256) {
        float4 v = xsrc[q];
        int r = q >> 5, d = (q & 31) << 2;
        xs[r][d] = v.x; xs[r][d + 1] = v.y; xs[r][d + 2] = v.z; xs[r][d + 3] = v.w;
    }
    __syncthreads();

    const int eb = t & 31, rb = t >> 5;
    const int e0 = eb * 4, rr0 = rb * 4;

    float acc_[4][4];
    #pragma unroll
    for (int ei = 0; ei < 4; ++ei) {
        float bv = bias[e0 + ei];
        #pragma unroll
        for (int ri = 0; ri < 4; ++ri) acc_[ri][ei] = bv;
    }

    for (int d4 = 0; d4 < 32; ++d4) {
        float wv[4][4];
        #pragma unroll
        for (int ei = 0; ei < 4; ++ei) {
            ushort4 u = *(const ushort4*)&W5[d4 * 256 + ei * 64 + ((eb ^ d4) & 31) * 4];
            wv[ei][0] = bf2f(u.x); wv[ei][1] = bf2f(u.y);
            wv[ei][2] = bf2f(u.z); wv[ei][3] = bf2f(u.w);
        }
        #pragma unroll
        for (int ri = 0; ri < 4; ++ri) {
            float4 xv = *(const float4*)&xs[rr0 + ri][d4 * 4];
            #pragma unroll
            for (int ei = 0; ei < 4; ++ei) {
                acc_[ri][ei] = fmaf(xv.x, wv[ei][0],
                               fmaf(xv.y, wv[ei][1],
                               fmaf(xv.z, wv[ei][2],
                               fmaf(xv.w, wv[ei][3], acc_[ri][ei]))));
            }
        }
    }

    float s[4] = {0.f, 0.f, 0.f, 0.f};
    #pragma unroll
    for (int ri = 0; ri < 4; ++ri) {
        ushort4 o;
        float v0 = bf2f(o.x = f2bf(acc_[ri][0]));
        float v1 = bf2f(o.y = f2bf(acc_[ri][1]));
        float v2 = bf2f(o.z = f2bf(acc_[ri][2]));
        float v3 = bf2f(o.w = f2bf(acc_[ri][3]));
        s[ri] = v0 * v0 + v1 * v1 + v2 * v2 + v3 * v3;
        *(ushort4*)&h[(r0 + rr0 + ri) * 128 + e0] = o;
    }
    #pragma unroll
    for (int ri = 0; ri < 4; ++ri) {
        #pragma unroll
        for (int m = 16; m > 0; m >>= 1) s[ri] += __shfl_xor(s[ri], m, 64);
    }
    if (eb == 0) {
        #pragma unroll
        for (int ri = 0; ri < 4; ++ri) sq[r0 + rr0 + ri] = s[ri];
    }
}

// ---------------- Kernel B: persistent 256-block pipelined gram ----------------
// 256 blocks = 1/CU, ONE round. Block: i-panel (256 rows, 64 KiB LDS) staged
// once; j-range of 1024 cols swept as 8 double-buffered 128-row subtiles
// (2 x 32 KiB). Per subtile: ds_read+MFMA(cur) -> issue STAGE(next) ->
// epilogue + nt stores -> barrier. The barrier's store drain IS the write-BW
// floor; next stage flies under it. XCD affinity pins each batch's 1 MiB
// panel to an XCD pair (R7-proven: FETCH ~4 MB).
__global__ __launch_bounds__(512, 2) void gram_kernel(
    const unsigned short* __restrict__ h, const float* __restrict__ sq,
    float* __restrict__ out)
{
    __shared__ __align__(16) unsigned short hsI[256 * 128];   // 64 KiB
    __shared__ __align__(16) unsigned short hsJ0[128 * 128];  // 32 KiB
    __shared__ __align__(16) unsigned short hsJ1[128 * 128];  // 32 KiB
    const int bid = blockIdx.x;                       // 256 blocks
    const int xcd = bid & 7;
    const int bb  = xcd >> 1;                         // batch -> XCD pair
    const int tloc = ((bid >> 3) << 1) | (xcd & 1);   // 0..63 within batch
    const int it = tloc >> 2, jr = tloc & 3;
    const int i0l = it * 256;                         // batch-local i row base
    const int j0l = jr * 1024;                        // batch-local j col base
    const long ibase_g = (long)bb * 4096 + i0l;
    const long jrow_g  = (long)bb * 4096 + j0l;
    const int t = threadIdx.x, w = t >> 6, lane = t & 63;
    const int l31 = lane & 31, lh = lane >> 5;
    const int wr = w >> 1, wc = w & 1;                // wave -> 64(i) x 64(j)
    const char* hb = (const char*)h;

    #define STAGE_I()                                                          \
        { _Pragma("unroll")                                                    \
          for (int q = 0; q < 8; ++q) {                                        \
            int p = (q * 512 + t) << 4; int row = p >> 8;                      \
            int cs = ((p >> 4) & 15) ^ (row & 15);                             \
            __builtin_amdgcn_global_load_lds(                                  \
                (gvoid_t*)(hb + ((ibase_g + row) << 8) + (cs << 4)),           \
                (lds_void_t*)(((char*)hsI) + (unsigned)p), 16, 0, 0); } }

    #define STAGE_J(dst, jtn)                                                  \
        { _Pragma("unroll")                                                    \
          for (int q = 0; q < 4; ++q) {                                        \
            int p = (q * 512 + t) << 4; int row = p >> 8;                      \
            int cs = ((p >> 4) & 15) ^ (row & 15);                             \
            __builtin_amdgcn_global_load_lds(                                  \
                (gvoid_t*)(hb + ((jrow_g + (jtn) * 128 + row) << 8) + (cs << 4)), \
                (lds_void_t*)(((char*)(dst)) + (unsigned)p), 16, 0, 0); } }

    STAGE_I();
    STAGE_J(hsJ0, 0);

    // sq_i per acc reg (C/D row = (reg&3)+8*(reg>>2)+4*lh), per rb
    float sqi_r[2][16];
    #pragma unroll
    for (int rb = 0; rb < 2; ++rb)
        #pragma unroll
        for (int reg = 0; reg < 16; ++reg)
            sqi_r[rb][reg] =
                sq[ibase_g + wr * 64 + rb * 32 + (reg & 3) + 8 * (reg >> 2) + 4 * lh];

    float* ob = out + ((size_t)bb << 24) + ((size_t)i0l << 12) + j0l;
    const char* hI = (const char*)hsI;

    __syncthreads();   // i-panel + j0 staged (drains vmcnt)

    for (int jt = 0; jt < 8; ++jt) {
        const char* hJ = (jt & 1) ? (const char*)hsJ1 : (const char*)hsJ0;

        f32x16 acc[2][2] = {};
        #pragma unroll
        for (int ks = 0; ks < 8; ++ks) {              // K = 8 x 16
            bf16x8 af[2], bg[2];
            #pragma unroll
            for (int rb = 0; rb < 2; ++rb) {
                int rowA = wr * 64 + rb * 32 + l31;
                int cA = ((ks * 2 + lh) ^ (rowA & 15)) << 4;
                af[rb] = *(const bf16x8*)(hI + (rowA << 8) + cA);
                int rowB = wc * 64 + rb * 32 + l31;
                int cB = ((ks * 2 + lh) ^ (rowB & 15)) << 4;
                bg[rb] = *(const bf16x8*)(hJ + (rowB << 8) + cB);
            }
            #pragma unroll
            for (int rb = 0; rb < 2; ++rb)
                #pragma unroll
                for (int nb = 0; nb < 2; ++nb)
                    acc[rb][nb] = __builtin_amdgcn_mfma_f32_32x32x16_bf16(
                        af[rb], bg[nb], acc[rb][nb], 0, 0, 0);
        }

        // prefetch next j-subtile: buffer (jt+1)&1 is free (last iter's barrier)
        if (jt < 7) { if (jt & 1) STAGE_J(hsJ0, jt + 1) else STAGE_J(hsJ1, jt + 1) }

        // epilogue + stores
        float sqj_n[2];
        #pragma unroll
        for (int nb = 0; nb < 2; ++nb)
            sqj_n[nb] = sq[jrow_g + jt * 128 + wc * 64 + nb * 32 + l31];

        #pragma unroll
        for (int rb = 0; rb < 2; ++rb) {
            #pragma unroll
            for (int reg = 0; reg < 16; ++reg) {
                int il = wr * 64 + rb * 32 + (reg & 3) + 8 * (reg >> 2) + 4 * lh;
                int grow = i0l + il;
                #pragma unroll
                for (int nb = 0; nb < 2; ++nb) {
                    int jl = jt * 128 + wc * 64 + nb * 32 + l31;
                    float d2 = fmaxf(fmaf(acc[rb][nb][reg], -2.0f,
                                          sqi_r[rb][reg] + sqj_n[nb]), 0.0f);
                    float val = __expf(-sqrtf(d2));
                    if (grow == j0l + jl) val = 1.0f;     // exact diagonal
                    __builtin_nontemporal_store(val, ob + ((long)il << 12) + jl);
                }
            }
        }
        __syncthreads();  // drains stores (write-BW floor) + next stage under it
    }
    #undef STAGE_I
    #undef STAGE_J
}

extern "C" void kernel_launch(void* const* d_in, const int* in_sizes, int n_in,
                              void* d_out, int out_size, void* d_ws, size_t ws_size,
                              hipStream_t stream) {
    const float* x = (const float*)d_in[0];   // [4,4096,128]
    const float* W = (const float*)d_in[1];   // [128,128]
    const float* b = (const float*)d_in[2];   // [128]
    float* out = (float*)d_out;               // [4,4096,4096]

    unsigned short* h = (unsigned short*)d_ws;                       // 16384*128 bf16
    float* sq = (float*)((char*)d_ws + (size_t)16384 * 128 * 2);     // 16384 fp32

    proj_kernel<<<dim3(16384 / KA_ROWS), dim3(256), 0, stream>>>(x, W, b, h, sq);
    gram_kernel<<<dim3(256), dim3(512), 0, stream>>>(h, sq, out);
}

// Round 13
// 88.068 us; speedup vs baseline: 1.4326x; 1.1250x over previous
//
#include <hip/hip_runtime.h>

// B=4, N=4096, D=128 fixed by the reference setup.
// d_ws layout: [0, 4MiB) h as bf16 bits (ushort), [4MiB, +64KiB) sq fp32.

typedef float  f32x4   __attribute__((ext_vector_type(4)));
typedef float  f32x16  __attribute__((ext_vector_type(16)));
typedef short  bf16x8  __attribute__((ext_vector_type(8)));
typedef __attribute__((address_space(3))) void       lds_void_t;
typedef const __attribute__((address_space(1))) void gvoid_t;

__device__ inline float bf2f(unsigned int u) {
    union { unsigned int i; float f; } c; c.i = u << 16; return c.f;
}
__device__ inline unsigned short f2bf(float f) {
    union { float f; unsigned int i; } c; c.f = f;
    unsigned int r = c.i + 0x7fffu + ((c.i >> 16) & 1u);   // RNE
    return (unsigned short)(r >> 16);
}

// ---------------- Kernel A: h = bf16(x @ W^T + b), plus sq[row] = ||h_row||^2 ----
#define KA_ROWS 32
__global__ __launch_bounds__(256) void proj_kernel(
    const float* __restrict__ x, const float* __restrict__ W,
    const float* __restrict__ bias, unsigned short* __restrict__ h,
    float* __restrict__ sq)
{
    __shared__ __align__(16) unsigned short W5[32 * 4 * 32 * 4]; // 32 KiB
    __shared__ float xs[KA_ROWS][132];
    const int t = threadIdx.x;
    const long r0 = (long)blockIdx.x * KA_ROWS;

    for (int q = t; q < 4096; q += 256) {
        float4 w4 = ((const float4*)W)[q];
        int e = q >> 5, d4 = q & 31;
        int eb = e >> 2, ei = e & 3;
        ushort4 o;
        o.x = f2bf(w4.x); o.y = f2bf(w4.y); o.z = f2bf(w4.z); o.w = f2bf(w4.w);
        *(ushort4*)&W5[d4 * 256 + ei * 64 + ((eb ^ d4) & 31) * 4] = o;
    }
    const float4* xsrc = (const float4*)(x + r0 * 128);
    for (int q = t; q < KA_ROWS * 32; q += 256) {
        float4 v = xsrc[q];
        int r = q >> 5, d = (q & 31) << 2;
        xs[r][d] = v.x; xs[r][d + 1] = v.y; xs[r][d + 2] = v.z; xs[r][d + 3] = v.w;
    }
    __syncthreads();

    const int eb = t & 31, rb = t >> 5;
    const int e0 = eb * 4, rr0 = rb * 4;

    float acc_[4][4];
    #pragma unroll
    for (int ei = 0; ei < 4; ++ei) {
        float bv = bias[e0 + ei];
        #pragma unroll
        for (int ri = 0; ri < 4; ++ri) acc_[ri][ei] = bv;
    }

    for (int d4 = 0; d4 < 32; ++d4) {
        float wv[4][4];
        #pragma unroll
        for (int ei = 0; ei < 4; ++ei) {
            ushort4 u = *(const ushort4*)&W5[d4 * 256 + ei * 64 + ((eb ^ d4) & 31) * 4];
            wv[ei][0] = bf2f(u.x); wv[ei][1] = bf2f(u.y);
            wv[ei][2] = bf2f(u.z); wv[ei][3] = bf2f(u.w);
        }
        #pragma unroll
        for (int ri = 0; ri < 4; ++ri) {
            float4 xv = *(const float4*)&xs[rr0 + ri][d4 * 4];
            #pragma unroll
            for (int ei = 0; ei < 4; ++ei) {
                acc_[ri][ei] = fmaf(xv.x, wv[ei][0],
                               fmaf(xv.y, wv[ei][1],
                               fmaf(xv.z, wv[ei][2],
                               fmaf(xv.w, wv[ei][3], acc_[ri][ei]))));
            }
        }
    }

    float s[4] = {0.f, 0.f, 0.f, 0.f};
    #pragma unroll
    for (int ri = 0; ri < 4; ++ri) {
        ushort4 o;
        float v0 = bf2f(o.x = f2bf(acc_[ri][0]));
        float v1 = bf2f(o.y = f2bf(acc_[ri][1]));
        float v2 = bf2f(o.z = f2bf(acc_[ri][2]));
        float v3 = bf2f(o.w = f2bf(acc_[ri][3]));
        s[ri] = v0 * v0 + v1 * v1 + v2 * v2 + v3 * v3;
        *(ushort4*)&h[(r0 + rr0 + ri) * 128 + e0] = o;
    }
    #pragma unroll
    for (int ri = 0; ri < 4; ++ri) {
        #pragma unroll
        for (int m = 16; m > 0; m >>= 1) s[ri] += __shfl_xor(s[ri], m, 64);
    }
    if (eb == 0) {
        #pragma unroll
        for (int ri = 0; ri < 4; ++ri) sq[r0 + rr0 + ri] = s[ri];
    }
}

// ---------------- Kernel B: R10 champion + fill-style dwordx4 flush ----------
// Identical to R10 (1024 blocks, 512 thr, 256x256 tile, both panels in LDS,
// one staging barrier, 1 block/CU) EXCEPT the store path: vals go to a
// [128][256] fp32 LDS staging buffer (reusing the dead i/j panels) and are
// flushed as 1 KB-contiguous nt dwordx4 per wave-instruction — the exact
// pattern the 6.9 TB/s fill kernel uses. Epilogue barriers are raw s_barrier
// + lgkmcnt(0) (NO vmcnt drain) so flush stores stay in flight across phases.
__global__ __launch_bounds__(512, 2) void gram_kernel(
    const unsigned short* __restrict__ h, const float* __restrict__ sq,
    float* __restrict__ out)
{
    __shared__ __align__(16) char smem[131072];       // 128 KiB
    unsigned short* hsI = (unsigned short*)smem;              // 64 KiB
    unsigned short* hsJ = (unsigned short*)(smem + 65536);    // 64 KiB
    float* stg = (float*)smem;                        // [128][256] reuse

    const int bid = blockIdx.x;                       // 1024 blocks
    const int xcd = bid & 7;
    const int bb  = xcd >> 1;                         // batch -> XCD pair
    const int tloc = ((bid >> 3) << 1) | (xcd & 1);   // 0..255 tile in batch
    const int it = tloc >> 4, jt = tloc & 15;
    const int i0 = bb * 4096 + it * 256;
    const int j0 = bb * 4096 + jt * 256;
    const int t = threadIdx.x, w = t >> 6, lane = t & 63;

    const char* hb = (const char*)h;
    #pragma unroll
    for (int q = 0; q < 8; ++q) {
        int p   = (q * 512 + t) << 4;                 // linear byte off in panel
        int row = p >> 8;                             // 256 B per row
        int c   = (p >> 4) & 15;
        int cs  = c ^ (row & 15);                     // inverse swizzle at source
        __builtin_amdgcn_global_load_lds(
            (gvoid_t*)(hb + ((long)(i0 + row) << 8) + (cs << 4)),
            (lds_void_t*)(((char*)hsI) + (unsigned)p), 16, 0, 0);
        __builtin_amdgcn_global_load_lds(
            (gvoid_t*)(hb + ((long)(j0 + row) << 8) + (cs << 4)),
            (lds_void_t*)(((char*)hsJ) + (unsigned)p), 16, 0, 0);
    }
    __syncthreads();

    const int wr = w >> 2, wc = w & 3;      // wave -> 128x64 quadrant
    const int l31 = lane & 31, lh = lane >> 5;
    f32x16 acc[4][2] = {};
    const char* hI = (const char*)hsI;
    const char* hJ = (const char*)hsJ;

    #pragma unroll
    for (int ks = 0; ks < 8; ++ks) {        // K = 8 x 16
        bf16x8 af[4], bg[2];
        #pragma unroll
        for (int rb = 0; rb < 4; ++rb) {
            int rowA = wr * 128 + rb * 32 + l31;
            int cA = ((ks * 2 + lh) ^ (rowA & 15)) << 4;
            af[rb] = *(const bf16x8*)(hI + (rowA << 8) + cA);
        }
        #pragma unroll
        for (int nb = 0; nb < 2; ++nb) {
            int rowB = wc * 64 + nb * 32 + l31;
            int cB = ((ks * 2 + lh) ^ (rowB & 15)) << 4;
            bg[nb] = *(const bf16x8*)(hJ + (rowB << 8) + cB);
        }
        #pragma unroll
        for (int rb = 0; rb < 4; ++rb)
            #pragma unroll
            for (int nb = 0; nb < 2; ++nb)
                acc[rb][nb] = __builtin_amdgcn_mfma_f32_32x32x16_bf16(
                    af[rb], bg[nb], acc[rb][nb], 0, 0, 0);
    }

    // ---- val compute in place (same math as R10) ----
    float sqj_r[2];
    #pragma unroll
    for (int nb = 0; nb < 2; ++nb) sqj_r[nb] = sq[j0 + wc * 64 + nb * 32 + l31];

    #pragma unroll
    for (int rb = 0; rb < 4; ++rb) {
        #pragma unroll
        for (int reg = 0; reg < 16; ++reg) {
            int il = wr * 128 + rb * 32 + (reg & 3) + 8 * (reg >> 2) + 4 * lh;
            float sqi_v = sq[i0 + il];
            #pragma unroll
            for (int nb = 0; nb < 2; ++nb) {
                int jl = wc * 64 + nb * 32 + l31;
                float d2 = fmaxf(fmaf(acc[rb][nb][reg], -2.0f, sqi_v + sqj_r[nb]), 0.0f);
                float val = __expf(-__builtin_amdgcn_sqrtf(d2));
                if (it == jt && il == jl) val = 1.0f;     // exact diagonal
                acc[rb][nb][reg] = val;
            }
        }
    }

    // ---- LDS-transposed flush: fill-style 1 KB dwordx4 nt stores ----
    float* ob = out + ((long)i0 << 12) + (jt << 8);

    asm volatile("s_waitcnt lgkmcnt(0)" ::: "memory");
    __builtin_amdgcn_s_barrier();           // all MFMA ds_reads done; stg free

    #pragma unroll
    for (int hh = 0; hh < 2; ++hh) {
        if (wr == hh) {                     // this wave's 128 rows = half hh
            #pragma unroll
            for (int rb = 0; rb < 4; ++rb)
                #pragma unroll
                for (int reg = 0; reg < 16; ++reg) {
                    int row = rb * 32 + (reg & 3) + 8 * (reg >> 2) + 4 * lh;
                    #pragma unroll
                    for (int nb = 0; nb < 2; ++nb)
                        stg[row * 256 + wc * 64 + nb * 32 + l31] = acc[rb][nb][reg];
                }
        }
        asm volatile("s_waitcnt lgkmcnt(0)" ::: "memory");
        __builtin_amdgcn_s_barrier();       // stg half ready (no vm drain)

        #pragma unroll
        for (int k = 0; k < 16; ++k) {      // each wave flushes 16 rows
            int r = w * 16 + k;
            f32x4 v = *(const f32x4*)&stg[r * 256 + (lane << 2)];
            __builtin_nontemporal_store(
                v, (f32x4*)(ob + ((long)(hh * 128 + r) << 12) + (lane << 2)));
        }
        asm volatile("s_waitcnt lgkmcnt(0)" ::: "memory");
        __builtin_amdgcn_s_barrier();       // stg reads done; writable again
    }
}

extern "C" void kernel_launch(void* const* d_in, const int* in_sizes, int n_in,
                              void* d_out, int out_size, void* d_ws, size_t ws_size,
                              hipStream_t stream) {
    const float* x = (const float*)d_in[0];   // [4,4096,128]
    const float* W = (const float*)d_in[1];   // [128,128]
    const float* b = (const float*)d_in[2];   // [128]
    float* out = (float*)d_out;               // [4,4096,4096]

    unsigned short* h = (unsigned short*)d_ws;                       // 16384*128 bf16
    float* sq = (float*)((char*)d_ws + (size_t)16384 * 128 * 2);     // 16384 fp32

    proj_kernel<<<dim3(16384 / KA_ROWS), dim3(256), 0, stream>>>(x, W, b, h, sq);
    gram_kernel<<<dim3(1024), dim3(512), 0, stream>>>(h, sq, out);
}